// Round 1
// baseline (440.593 us; speedup 1.0000x reference)
//
#include <hip/hip_runtime.h>
#include <cstdint>
#include <cstddef>

#define NN    8192      // N
#define NIN   4096      // N_IN
#define BB    16        // B
#define BN    131072    // B*N
#define ITILE 128       // rows per i-chunk
#define CINT  64        // NN/ITILE
#define CEXT  32        // NIN/ITILE
#define CTOT  96        // CINT+CEXT

static constexpr float ALPHA_F = 0.9512294245007140f;            // fl32(exp(-0.05))
static constexpr float RHOA_F  = 0.9950124791926823f;            // fl32(exp(-0.005))
static constexpr float SCALE_F = (float)(1.0 - 0.9512294245007140); // fl32(1 - alpha_f64)

// ---------------------------------------------------------------------------
// k_prep: elementwise ALIF update + base membrane + spike bit-masks
// out layout: [X (BN) | V_new (BN) | a_new (BN) | Xd_new (8*BN)]
// ---------------------------------------------------------------------------
__global__ __launch_bounds__(256) void k_prep(
    const float* __restrict__ V, const float* __restrict__ a,
    const float* __restrict__ Xd, const float* __restrict__ Xext,
    float* __restrict__ out,
    unsigned* __restrict__ mask_int, unsigned* __restrict__ mask_ext)
{
    const int t = blockIdx.x * 256 + threadIdx.x;   // t in [0, BN)
    const float v  = V[t];
    const float av = a[t];
    // exactness-critical: no FMA contraction on the threshold compare
    const float th = __fadd_rn(1.0f, __fmul_rn(1.8f, av));
    const bool  spike = (v >= th);
    const float x = spike ? 1.0f : 0.0f;
    out[t]          = x;                                          // X
    out[BN + t]     = spike ? 0.0f : __fmul_rn(ALPHA_F, v);       // V base (current added later)
    out[2*BN + t]   = __fadd_rn(__fmul_rn(RHOA_F, av), x);        // a_new
    out[3*BN + t]   = x;                                          // Xd_new[0]

    if (t < NN) {                       // build internal mask from Xd[-1]
        unsigned m = 0;
        #pragma unroll
        for (int b = 0; b < BB; ++b)
            m |= (Xd[7*BN + b*NN + t] > 0.5f) ? (1u << b) : 0u;
        mask_int[t] = m;
    } else if (t < NN + NIN) {          // external mask from Xext
        const int i = t - NN;
        unsigned m = 0;
        #pragma unroll
        for (int b = 0; b < BB; ++b)
            m |= (Xext[b*NIN + i] > 0.5f) ? (1u << b) : 0u;
        mask_ext[i] = m;
    }
}

// ---------------------------------------------------------------------------
// k_shift: Xd_new[1:8] = Xd[0:7]  (7*BN floats, float4 vectorized)
// ---------------------------------------------------------------------------
__global__ __launch_bounds__(256) void k_shift(const float4* __restrict__ src,
                                               float4* __restrict__ dst)
{
    const int t = blockIdx.x * 256 + threadIdx.x;   // t in [0, 7*BN/4)
    dst[t] = src[t];
}

// ---------------------------------------------------------------------------
// k_mm: sparse-row spike matmul. grid = (16 n-tiles, 96 i-chunks).
// blockIdx.y < CINT -> W_int chunk; else W_ext chunk.
// Each thread owns 2 columns for all 16 batches (acc[16] float2 in regs).
// Rows with mask==0 are skipped uniformly (no HBM fetch).
// ---------------------------------------------------------------------------
__device__ __forceinline__ void accrow(float2 (&acc)[BB], unsigned m, float wx, float wy)
{
    #pragma unroll
    for (int b = 0; b < BB; ++b) {
        const float f = (float)((m >> b) & 1u);
        acc[b].x = __builtin_fmaf(wx, f, acc[b].x);
        acc[b].y = __builtin_fmaf(wy, f, acc[b].y);
    }
}

__global__ __launch_bounds__(256) void k_mm(
    const float* __restrict__ Wint, const float* __restrict__ Wext,
    const unsigned* __restrict__ mask_int, const unsigned* __restrict__ mask_ext,
    float* __restrict__ dst, int atomic_mode)
{
    const int tid   = threadIdx.x;
    const int chunk = blockIdx.y;
    const bool is_int = (chunk < CINT);
    const float*    W    = is_int ? Wint : Wext;
    const unsigned* mask = is_int ? mask_int : mask_ext;
    const int i0 = (is_int ? chunk : (chunk - CINT)) * ITILE;

    __shared__ unsigned sm[ITILE];
    if (tid < ITILE) sm[tid] = mask[i0 + tid];
    __syncthreads();

    const int n = (blockIdx.x << 9) + (tid << 1);   // 512-col tile, 2 cols/thread
    float2 acc[BB];
    #pragma unroll
    for (int b = 0; b < BB; ++b) acc[b] = make_float2(0.f, 0.f);

    const float* Wp = W + (size_t)i0 * NN + n;
    float2 w0 = make_float2(0.f,0.f), w1 = w0, w2 = w0, w3 = w0;

    for (int ii = 0; ii < ITILE; ii += 4) {
        const unsigned m0 = (unsigned)__builtin_amdgcn_readfirstlane((int)sm[ii+0]);
        const unsigned m1 = (unsigned)__builtin_amdgcn_readfirstlane((int)sm[ii+1]);
        const unsigned m2 = (unsigned)__builtin_amdgcn_readfirstlane((int)sm[ii+2]);
        const unsigned m3 = (unsigned)__builtin_amdgcn_readfirstlane((int)sm[ii+3]);
        // batch the (conditional) loads ahead of the FMAs for MLP
        if (m0) w0 = *(const float2*)(Wp + 0*(size_t)NN);
        if (m1) w1 = *(const float2*)(Wp + 1*(size_t)NN);
        if (m2) w2 = *(const float2*)(Wp + 2*(size_t)NN);
        if (m3) w3 = *(const float2*)(Wp + 3*(size_t)NN);
        if (m0) accrow(acc, m0, w0.x, w0.y);
        if (m1) accrow(acc, m1, w1.x, w1.y);
        if (m2) accrow(acc, m2, w2.x, w2.y);
        if (m3) accrow(acc, m3, w3.x, w3.y);
        Wp += 4*(size_t)NN;
    }

    if (atomic_mode) {
        // fallback: accumulate straight into V_new region of d_out
        float* o = dst + n;
        #pragma unroll
        for (int b = 0; b < BB; ++b) {
            unsafeAtomicAdd(o + (size_t)b*NN + 0, SCALE_F * acc[b].x);
            unsafeAtomicAdd(o + (size_t)b*NN + 1, SCALE_F * acc[b].y);
        }
    } else {
        float* p = dst + (size_t)chunk * BN + n;
        #pragma unroll
        for (int b = 0; b < BB; ++b)
            *(float2*)(p + (size_t)b*NN) = acc[b];
    }
}

// ---------------------------------------------------------------------------
// k_fin: V_new += SCALE * sum over 96 partials
// ---------------------------------------------------------------------------
__global__ __launch_bounds__(256) void k_fin(float* __restrict__ outV,
                                             const float* __restrict__ part)
{
    const int t4 = blockIdx.x * 256 + threadIdx.x;  // [0, BN/4)
    float4 s = make_float4(0.f, 0.f, 0.f, 0.f);
    #pragma unroll 8
    for (int c = 0; c < CTOT; ++c) {
        const float4 p = ((const float4*)(part + (size_t)c * BN))[t4];
        s.x += p.x; s.y += p.y; s.z += p.z; s.w += p.w;
    }
    float4 v = ((float4*)outV)[t4];
    v.x = __builtin_fmaf(SCALE_F, s.x, v.x);
    v.y = __builtin_fmaf(SCALE_F, s.y, v.y);
    v.z = __builtin_fmaf(SCALE_F, s.z, v.z);
    v.w = __builtin_fmaf(SCALE_F, s.w, v.w);
    ((float4*)outV)[t4] = v;
}

// ---------------------------------------------------------------------------
extern "C" void kernel_launch(void* const* d_in, const int* in_sizes, int n_in,
                              void* d_out, int out_size, void* d_ws, size_t ws_size,
                              hipStream_t stream)
{
    const float* V    = (const float*)d_in[0];
    const float* a    = (const float*)d_in[1];
    const float* Xd   = (const float*)d_in[2];
    const float* Xext = (const float*)d_in[3];
    const float* Wint = (const float*)d_in[4];
    const float* Wext = (const float*)d_in[5];
    float* out = (float*)d_out;

    unsigned* mask_int = (unsigned*)d_ws;
    unsigned* mask_ext = mask_int + NN;
    float*    part     = (float*)((char*)d_ws + 65536);
    const size_t need  = 65536 + (size_t)CTOT * BN * sizeof(float);
    const int atomic_mode = (ws_size < need) ? 1 : 0;

    k_prep<<<BN/256, 256, 0, stream>>>(V, a, Xd, Xext, out, mask_int, mask_ext);
    k_shift<<<(7*BN/4)/256, 256, 0, stream>>>((const float4*)Xd,
                                              (float4*)(out + (size_t)4*BN));
    float* mmdst = atomic_mode ? (out + BN) : part;
    k_mm<<<dim3(16, CTOT), 256, 0, stream>>>(Wint, Wext, mask_int, mask_ext,
                                             mmdst, atomic_mode);
    if (!atomic_mode)
        k_fin<<<BN/4/256, 256, 0, stream>>>(out + BN, part);
}

// Round 2
// 429.327 us; speedup vs baseline: 1.0262x; 1.0262x over previous
//
#include <hip/hip_runtime.h>
#include <cstdint>
#include <cstddef>

#define NN    8192      // N
#define NIN   4096      // N_IN
#define BB    16        // B
#define BN    131072    // B*N
#define NCH   32        // partial chunks total
#define NCHI  21        // chunks over int list (expected 2:1 row ratio)
#define NCHE  11        // chunks over ext list

static constexpr float ALPHA_F = 0.9512294245007140f;               // fl32(exp(-0.05))
static constexpr float RHOA_F  = 0.9950124791926823f;               // fl32(exp(-0.005))
static constexpr float SCALE_F = (float)(1.0 - 0.9512294245007140); // fl32(1 - alpha)

// ---------------------------------------------------------------------------
// k_prep: elementwise ALIF update + base membrane + per-row spike bit-masks
// out layout: [X (BN) | V_new (BN) | a_new (BN) | Xd_new (8*BN)]
// ---------------------------------------------------------------------------
__global__ __launch_bounds__(256) void k_prep(
    const float* __restrict__ V, const float* __restrict__ a,
    const float* __restrict__ Xd, const float* __restrict__ Xext,
    float* __restrict__ out,
    unsigned* __restrict__ mask_int, unsigned* __restrict__ mask_ext)
{
    const int t = blockIdx.x * 256 + threadIdx.x;   // t in [0, BN)
    const float v  = V[t];
    const float av = a[t];
    // exactness-critical: no FMA contraction on the threshold compare
    const float th = __fadd_rn(1.0f, __fmul_rn(1.8f, av));
    const bool  spike = (v >= th);
    const float x = spike ? 1.0f : 0.0f;
    out[t]          = x;                                          // X
    out[BN + t]     = spike ? 0.0f : __fmul_rn(ALPHA_F, v);       // V base (current added later)
    out[2*BN + t]   = __fadd_rn(__fmul_rn(RHOA_F, av), x);        // a_new
    out[3*BN + t]   = x;                                          // Xd_new[0]

    if (t < NN) {                       // internal mask from Xd[-1]
        unsigned m = 0;
        #pragma unroll
        for (int b = 0; b < BB; ++b)
            m |= (Xd[7*BN + b*NN + t] > 0.5f) ? (1u << b) : 0u;
        mask_int[t] = m;
    } else if (t < NN + NIN) {          // external mask from Xext
        const int i = t - NN;
        unsigned m = 0;
        #pragma unroll
        for (int b = 0; b < BB; ++b)
            m |= (Xext[b*NIN + i] > 0.5f) ? (1u << b) : 0u;
        mask_ext[i] = m;
    }
}

// ---------------------------------------------------------------------------
// k_compact: deterministic single-block stream compaction of active rows.
// entry = (row << 16) | mask16.  cnt[0]=int count, cnt[1]=ext count.
// ---------------------------------------------------------------------------
__global__ __launch_bounds__(1024) void k_compact(
    const unsigned* __restrict__ mask_int, const unsigned* __restrict__ mask_ext,
    unsigned* __restrict__ cnt,
    unsigned* __restrict__ list_int, unsigned* __restrict__ list_ext)
{
    __shared__ unsigned wsum[16];
    __shared__ unsigned stot;
    const int t = threadIdx.x;
    const int wave = t >> 6, lane = t & 63;

    unsigned base = 0;
    #pragma unroll 1
    for (int r = 0; r < 8; ++r) {                       // 8*1024 = 8192 int rows
        const int row = r * 1024 + t;
        const unsigned m = mask_int[row];
        const unsigned long long bal = __ballot(m != 0);
        const unsigned pre = __popcll(bal & ((1ull << lane) - 1ull));
        if (lane == 0) wsum[wave] = (unsigned)__popcll(bal);
        __syncthreads();
        if (t == 0) {
            unsigned s = 0;
            for (int i = 0; i < 16; ++i) { unsigned c = wsum[i]; wsum[i] = s; s += c; }
            stot = s;
        }
        __syncthreads();
        if (m) list_int[base + wsum[wave] + pre] = ((unsigned)row << 16) | m;
        base += stot;
        __syncthreads();
    }
    if (t == 0) cnt[0] = base;

    base = 0;
    #pragma unroll 1
    for (int r = 0; r < 4; ++r) {                       // 4*1024 = 4096 ext rows
        const int row = r * 1024 + t;
        const unsigned m = mask_ext[row];
        const unsigned long long bal = __ballot(m != 0);
        const unsigned pre = __popcll(bal & ((1ull << lane) - 1ull));
        if (lane == 0) wsum[wave] = (unsigned)__popcll(bal);
        __syncthreads();
        if (t == 0) {
            unsigned s = 0;
            for (int i = 0; i < 16; ++i) { unsigned c = wsum[i]; wsum[i] = s; s += c; }
            stot = s;
        }
        __syncthreads();
        if (m) list_ext[base + wsum[wave] + pre] = ((unsigned)row << 16) | m;
        base += stot;
        __syncthreads();
    }
    if (t == 0) cnt[1] = base;
}

// ---------------------------------------------------------------------------
// k_shift: Xd_new[1:8] = Xd[0:7]  (7*BN floats, float4 vectorized)
// ---------------------------------------------------------------------------
__global__ __launch_bounds__(256) void k_shift(const float4* __restrict__ src,
                                               float4* __restrict__ dst)
{
    const int t = blockIdx.x * 256 + threadIdx.x;   // t in [0, 7*BN/4)
    dst[t] = src[t];
}

// ---------------------------------------------------------------------------
// k_mm: branch-free compacted-row matmul.
// grid = (16 col-tiles of 512, NCH chunks). Chunk y<NCHI slices the int list,
// else the ext list. 8-deep unrolled load pipeline; pad entries = row0/mask0.
// ---------------------------------------------------------------------------
__device__ __forceinline__ void accrow(float2 (&acc)[BB], unsigned m, float wx, float wy)
{
    #pragma unroll
    for (int b = 0; b < BB; ++b) {
        const float f = (float)((m >> b) & 1u);
        acc[b].x = __builtin_fmaf(wx, f, acc[b].x);
        acc[b].y = __builtin_fmaf(wy, f, acc[b].y);
    }
}

__global__ __launch_bounds__(256) void k_mm(
    const float* __restrict__ Wint, const float* __restrict__ Wext,
    const unsigned* __restrict__ cnt,
    const unsigned* __restrict__ list_int, const unsigned* __restrict__ list_ext,
    float* __restrict__ part)
{
    const int tid = threadIdx.x;
    const int y   = blockIdx.y;
    const bool is_int = (y < NCHI);
    const float*    W    = is_int ? Wint : Wext;
    const unsigned* list = is_int ? list_int : list_ext;
    const unsigned  np_  = is_int ? NCHI : NCHE;
    const unsigned  pi   = is_int ? (unsigned)y : (unsigned)(y - NCHI);
    const unsigned  c    = cnt[is_int ? 0 : 1];
    const unsigned  lo   = (pi * c) / np_;
    const unsigned  hi   = ((pi + 1) * c) / np_;

    const int n = (blockIdx.x << 9) + (tid << 1);   // 2 cols/thread, 512-col tile

    float2 acc[BB];
    #pragma unroll
    for (int b = 0; b < BB; ++b) acc[b] = make_float2(0.f, 0.f);

    __shared__ unsigned sm[256];

    for (unsigned base = lo; base < hi; base += 256) {
        const unsigned idx = base + tid;
        sm[tid] = (idx < hi) ? list[idx] : 0u;      // pad: row 0, mask 0 (harmless)
        __syncthreads();
        const unsigned tile  = min(256u, hi - base);
        const unsigned tile8 = (tile + 7u) & ~7u;
        for (unsigned j = 0; j < tile8; j += 8) {
            unsigned e[8];
            float2   w[8];
            #pragma unroll
            for (int k = 0; k < 8; ++k) e[k] = sm[j + k];
            #pragma unroll
            for (int k = 0; k < 8; ++k)
                w[k] = *(const float2*)(W + (size_t)(e[k] >> 16) * NN + n);
            #pragma unroll
            for (int k = 0; k < 8; ++k)
                accrow(acc, e[k] & 0xffffu, w[k].x, w[k].y);
        }
        __syncthreads();
    }

    float* p = part + (size_t)y * BN + n;
    #pragma unroll
    for (int b = 0; b < BB; ++b)
        *(float2*)(p + (size_t)b * NN) = acc[b];
}

// ---------------------------------------------------------------------------
// k_fin: V_new += SCALE * sum over NCH partials
// ---------------------------------------------------------------------------
__global__ __launch_bounds__(256) void k_fin(float* __restrict__ outV,
                                             const float* __restrict__ part)
{
    const int t4 = blockIdx.x * 256 + threadIdx.x;  // [0, BN/4)
    float4 s = make_float4(0.f, 0.f, 0.f, 0.f);
    #pragma unroll 8
    for (int c = 0; c < NCH; ++c) {
        const float4 p = ((const float4*)(part + (size_t)c * BN))[t4];
        s.x += p.x; s.y += p.y; s.z += p.z; s.w += p.w;
    }
    float4 v = ((float4*)outV)[t4];
    v.x = __builtin_fmaf(SCALE_F, s.x, v.x);
    v.y = __builtin_fmaf(SCALE_F, s.y, v.y);
    v.z = __builtin_fmaf(SCALE_F, s.z, v.z);
    v.w = __builtin_fmaf(SCALE_F, s.w, v.w);
    ((float4*)outV)[t4] = v;
}

// ---------------------------------------------------------------------------
extern "C" void kernel_launch(void* const* d_in, const int* in_sizes, int n_in,
                              void* d_out, int out_size, void* d_ws, size_t ws_size,
                              hipStream_t stream)
{
    const float* V    = (const float*)d_in[0];
    const float* a    = (const float*)d_in[1];
    const float* Xd   = (const float*)d_in[2];
    const float* Xext = (const float*)d_in[3];
    const float* Wint = (const float*)d_in[4];
    const float* Wext = (const float*)d_in[5];
    float* out = (float*)d_out;

    // ws layout
    unsigned* cnt      = (unsigned*)d_ws;                       // 2 u32
    unsigned* mask_int = (unsigned*)((char*)d_ws + 256);        // 8192 u32
    unsigned* mask_ext = mask_int + NN;                         // 4096 u32
    unsigned* list_int = mask_ext + NIN;                        // 8192 u32
    unsigned* list_ext = list_int + NN;                         // 4096 u32
    float*    part     = (float*)((char*)d_ws + 131072);        // NCH*BN f32 (16.8 MB)

    k_prep<<<BN/256, 256, 0, stream>>>(V, a, Xd, Xext, out, mask_int, mask_ext);
    k_compact<<<1, 1024, 0, stream>>>(mask_int, mask_ext, cnt, list_int, list_ext);
    k_shift<<<(7*BN/4)/256, 256, 0, stream>>>((const float4*)Xd,
                                              (float4*)(out + (size_t)4*BN));
    k_mm<<<dim3(16, NCH), 256, 0, stream>>>(Wint, Wext, cnt, list_int, list_ext, part);
    k_fin<<<BN/4/256, 256, 0, stream>>>(out + BN, part);
}

// Round 3
// 426.452 us; speedup vs baseline: 1.0332x; 1.0067x over previous
//
#include <hip/hip_runtime.h>
#include <cstdint>
#include <cstddef>

#define NN    8192      // N
#define NIN   4096      // N_IN
#define BB    16        // B
#define BN    131072    // B*N
#define ROWCH 512       // rows per chunk
#define NCHI  16        // int chunks  (8192/512)
#define NCHE  8         // ext chunks  (4096/512)
#define NCH   24        // total chunks

static constexpr float ALPHA_F = 0.9512294245007140f;               // fl32(exp(-0.05))
static constexpr float RHOA_F  = 0.9950124791926823f;               // fl32(exp(-0.005))
static constexpr float SCALE_F = (float)(1.0 - 0.9512294245007140); // fl32(1 - alpha)

// ---------------------------------------------------------------------------
// k_aux: (a) per-row spike bit-masks from Xd[-1] / Xext, (b) delay-buffer
// shift Xd_new[1:8] = Xd[0:7] (float4). Grid-stride over 7*BN/4 float4s.
// ---------------------------------------------------------------------------
__global__ __launch_bounds__(256) void k_aux(
    const float* __restrict__ Xd, const float* __restrict__ Xext,
    float* __restrict__ out,
    unsigned* __restrict__ mask_int, unsigned* __restrict__ mask_ext)
{
    const int t = blockIdx.x * 256 + threadIdx.x;   // [0, 7*BN/4)

    if (t < NN) {                       // internal mask from Xd[-1]
        unsigned m = 0;
        #pragma unroll
        for (int b = 0; b < BB; ++b)
            m |= (Xd[7*BN + b*NN + t] > 0.5f) ? (1u << b) : 0u;
        mask_int[t] = m;
    } else if (t < NN + NIN) {          // external mask from Xext
        const int i = t - NN;
        unsigned m = 0;
        #pragma unroll
        for (int b = 0; b < BB; ++b)
            m |= (Xext[b*NIN + i] > 0.5f) ? (1u << b) : 0u;
        mask_ext[i] = m;
    }

    // shift: Xd_new[1:8] = Xd[0:7]
    ((float4*)(out + (size_t)4*BN))[t] = ((const float4*)Xd)[t];
}

// ---------------------------------------------------------------------------
// k_mm: spike-sparse matmul with per-block row compaction.
// grid = (16 col-tiles of 512, NCH chunks). y<NCHI -> W_int rows, else W_ext.
// Each block: stage 512 masks -> compact active rows in LDS -> branch-free
// 8-deep unrolled load/FMA pipeline. Partials to ws.
// ---------------------------------------------------------------------------
__device__ __forceinline__ void accrow(float2 (&acc)[BB], unsigned m, float wx, float wy)
{
    #pragma unroll
    for (int b = 0; b < BB; ++b) {
        const float f = (float)((m >> b) & 1u);
        acc[b].x = __builtin_fmaf(wx, f, acc[b].x);
        acc[b].y = __builtin_fmaf(wy, f, acc[b].y);
    }
}

__global__ __launch_bounds__(256) void k_mm(
    const float* __restrict__ Wint, const float* __restrict__ Wext,
    const unsigned* __restrict__ mask_int, const unsigned* __restrict__ mask_ext,
    float* __restrict__ part)
{
    const int tid  = threadIdx.x;
    const int y    = blockIdx.y;
    const int wave = tid >> 6, lane = tid & 63;
    const bool is_int = (y < NCHI);
    const float*    W    = is_int ? Wint : Wext;
    const unsigned* mask = is_int ? mask_int : mask_ext;
    const int base_row   = (is_int ? y : (y - NCHI)) * ROWCH;

    __shared__ unsigned sc[ROWCH + 8];   // compacted (localrow<<16)|mask
    __shared__ unsigned wsum[4];

    // --- per-block compaction of 512 masks (2 rounds of 256) ---
    unsigned total = 0;
    #pragma unroll
    for (int r = 0; r < 2; ++r) {
        const int idx = r * 256 + tid;
        const unsigned m = mask[base_row + idx];
        const unsigned long long bal = __ballot(m != 0);
        const unsigned pre = __popcll(bal & ((1ull << lane) - 1ull));
        if (lane == 0) wsum[wave] = (unsigned)__popcll(bal);
        __syncthreads();
        const unsigned w0 = wsum[0], w1 = wsum[1], w2 = wsum[2], w3 = wsum[3];
        unsigned bw = 0;
        if (wave > 0) bw += w0;
        if (wave > 1) bw += w1;
        if (wave > 2) bw += w2;
        if (m) sc[total + bw + pre] = ((unsigned)idx << 16) | m;
        total += w0 + w1 + w2 + w3;
        __syncthreads();
    }
    if (tid < 8) sc[total + tid] = 0u;   // zero-pad (row 0, mask 0: harmless)
    __syncthreads();
    const unsigned nrow8 = (total + 7u) & ~7u;

    // --- branch-free 8-deep pipeline over active rows ---
    const int n = (blockIdx.x << 9) + (tid << 1);   // 2 cols/thread, 512-col tile
    float2 acc[BB];
    #pragma unroll
    for (int b = 0; b < BB; ++b) acc[b] = make_float2(0.f, 0.f);

    const float* Wb = W + (size_t)base_row * NN + n;
    for (unsigned j = 0; j < nrow8; j += 8) {
        unsigned e[8];
        float2   w[8];
        #pragma unroll
        for (int k = 0; k < 8; ++k) e[k] = sc[j + k];
        #pragma unroll
        for (int k = 0; k < 8; ++k)
            w[k] = *(const float2*)(Wb + (size_t)(e[k] >> 16) * NN);
        #pragma unroll
        for (int k = 0; k < 8; ++k)
            accrow(acc, e[k] & 0xffffu, w[k].x, w[k].y);
    }

    float* p = part + (size_t)y * BN + n;
    #pragma unroll
    for (int b = 0; b < BB; ++b)
        *(float2*)(p + (size_t)b * NN) = acc[b];
}

// ---------------------------------------------------------------------------
// k_fin: fused ALIF elementwise + partial reduction.
// out layout: [X (BN) | V_new (BN) | a_new (BN) | Xd_new (8*BN)]
// ---------------------------------------------------------------------------
__global__ __launch_bounds__(256) void k_fin(
    const float* __restrict__ V, const float* __restrict__ a,
    const float* __restrict__ part, float* __restrict__ out)
{
    const int t4 = blockIdx.x * 256 + threadIdx.x;  // [0, BN/4)

    float4 s = make_float4(0.f, 0.f, 0.f, 0.f);
    #pragma unroll 8
    for (int c = 0; c < NCH; ++c) {
        const float4 p = ((const float4*)(part + (size_t)c * BN))[t4];
        s.x += p.x; s.y += p.y; s.z += p.z; s.w += p.w;
    }

    const float4 v4 = ((const float4*)V)[t4];
    const float4 a4 = ((const float4*)a)[t4];
    float4 x4, vn4, an4;
    {
        const float* vv = &v4.x; const float* aa = &a4.x;
        float* xx = &x4.x; float* vn = &vn4.x; float* an = &an4.x;
        const float* ss = &s.x;
        #pragma unroll
        for (int k = 0; k < 4; ++k) {
            // exactness-critical: no FMA contraction on the threshold compare
            const float th = __fadd_rn(1.0f, __fmul_rn(1.8f, aa[k]));
            const bool spike = (vv[k] >= th);
            const float x = spike ? 1.0f : 0.0f;
            xx[k] = x;
            float v_new = spike ? 0.0f : __fmul_rn(ALPHA_F, vv[k]);
            vn[k] = __builtin_fmaf(SCALE_F, ss[k], v_new);
            an[k] = __fadd_rn(__fmul_rn(RHOA_F, aa[k]), x);
        }
    }
    ((float4*)out)[t4]                       = x4;   // X
    ((float4*)(out + (size_t)BN))[t4]        = vn4;  // V_new
    ((float4*)(out + (size_t)2*BN))[t4]      = an4;  // a_new
    ((float4*)(out + (size_t)3*BN))[t4]      = x4;   // Xd_new[0]
}

// ---------------------------------------------------------------------------
extern "C" void kernel_launch(void* const* d_in, const int* in_sizes, int n_in,
                              void* d_out, int out_size, void* d_ws, size_t ws_size,
                              hipStream_t stream)
{
    const float* V    = (const float*)d_in[0];
    const float* a    = (const float*)d_in[1];
    const float* Xd   = (const float*)d_in[2];
    const float* Xext = (const float*)d_in[3];
    const float* Wint = (const float*)d_in[4];
    const float* Wext = (const float*)d_in[5];
    float* out = (float*)d_out;

    unsigned* mask_int = (unsigned*)d_ws;                    // 8192 u32
    unsigned* mask_ext = mask_int + NN;                      // 4096 u32
    float*    part     = (float*)((char*)d_ws + 65536);      // NCH*BN f32 (12.6 MB)

    k_aux<<<(7*BN/4)/256, 256, 0, stream>>>(Xd, Xext, out, mask_int, mask_ext);
    k_mm<<<dim3(16, NCH), 256, 0, stream>>>(Wint, Wext, mask_int, mask_ext, part);
    k_fin<<<BN/4/256, 256, 0, stream>>>(V, a, part, out);
}